// Round 9
// baseline (259.952 us; speedup 1.0000x reference)
//
#include <hip/hip_runtime.h>
#include <hip/hip_bf16.h>
#include <stdint.h>

#define BATCH 2
#define TT 2048
#define CC 1024
#define NH 16
#define HD 64

typedef __attribute__((ext_vector_type(8))) short short8;
typedef __attribute__((ext_vector_type(4))) short sh4;
typedef __attribute__((ext_vector_type(4))) float f32x4;

#define MFMA16 __builtin_amdgcn_mfma_f32_16x16x32_bf16

__device__ __forceinline__ short f2bf(float f) {
  union { float f; unsigned u; } x;
  x.f = f;
  unsigned r = x.u + 0x7FFFu + ((x.u >> 16) & 1u);
  return (short)(r >> 16);
}

// ---------------------------------------------------------------------------
// Fused prep: blocks [0,2048) cast x fp32->bf16; [2048,2816) transpose W_attn;
// [2816,3072) transpose W_proj. 256 threads.
// ---------------------------------------------------------------------------
__device__ __forceinline__ void transpose_cast_tile(
    const float* __restrict__ W, short* __restrict__ Wt, int K, int N,
    int n0, int k0, int tid) {
  __shared__ __align__(16) float Ls[64][68];
  {
    const int r = tid >> 4, c4 = (tid & 15) * 4;
#pragma unroll
    for (int p = 0; p < 4; ++p) {
      const float4 v = *reinterpret_cast<const float4*>(
          &W[(size_t)(k0 + r + p * 16) * N + n0 + c4]);
      *reinterpret_cast<float4*>(&Ls[r + p * 16][c4]) = v;
    }
  }
  __syncthreads();
  {
    const int n = tid >> 2;
    const int kk0 = (tid & 3) * 16;
#pragma unroll
    for (int half = 0; half < 2; ++half) {
      short8 o;
#pragma unroll
      for (int t = 0; t < 8; ++t) o[t] = f2bf(Ls[kk0 + half * 8 + t][n]);
      *reinterpret_cast<short8*>(&Wt[(size_t)(n0 + n) * K + k0 + kk0 + half * 8]) = o;
    }
  }
}

__global__ __launch_bounds__(256) void prep_fused(
    const float* __restrict__ x, short* __restrict__ xb,
    const float* __restrict__ W_attn, short* __restrict__ wat,
    const float* __restrict__ W_proj, short* __restrict__ wpt) {
  const int blk = blockIdx.x;
  const int tid = threadIdx.x;
  if (blk < 2048) {
    const int i = (blk * 256 + tid) * 8;
    const float4 a = *reinterpret_cast<const float4*>(&x[i]);
    const float4 b = *reinterpret_cast<const float4*>(&x[i + 4]);
    short8 o;
    o[0] = f2bf(a.x); o[1] = f2bf(a.y); o[2] = f2bf(a.z); o[3] = f2bf(a.w);
    o[4] = f2bf(b.x); o[5] = f2bf(b.y); o[6] = f2bf(b.z); o[7] = f2bf(b.w);
    *reinterpret_cast<short8*>(&xb[i]) = o;
  } else if (blk < 2816) {
    const int b2 = blk - 2048;
    transpose_cast_tile(W_attn, wat, CC, 3 * CC, (b2 % 48) * 64,
                        (b2 / 48) * 64, tid);
  } else {
    const int b3 = blk - 2816;
    transpose_cast_tile(W_proj, wpt, CC, CC, (b3 % 16) * 64, (b3 / 16) * 64,
                        tid);
  }
}

// ---------------------------------------------------------------------------
// v slice of qkv -> vT[b][h][d][s]  (bf16), 64x64 tiles through LDS
// ---------------------------------------------------------------------------
__global__ __launch_bounds__(256) void transpose_v(
    const short* __restrict__ qkv, short* __restrict__ vT) {
  __shared__ __align__(16) short Ls[64][72];
  const int s0 = blockIdx.x * 64;
  const int bh = blockIdx.y, b = bh >> 4, h = bh & 15;
  const int tid = threadIdx.x;
  const int r = tid >> 3, c = (tid & 7) * 8;
#pragma unroll
  for (int p = 0; p < 2; ++p) {
    *reinterpret_cast<short8*>(&Ls[r + p * 32][c]) =
        *reinterpret_cast<const short8*>(
            &qkv[(size_t)(b * TT + s0 + r + p * 32) * (3 * CC) + 2 * CC +
                 h * HD + c]);
  }
  __syncthreads();
  const int d = tid >> 2, ss = (tid & 3) * 16;
  short8 o0, o1;
#pragma unroll
  for (int t = 0; t < 8; ++t) { o0[t] = Ls[ss + t][d]; o1[t] = Ls[ss + 8 + t][d]; }
  short* dst = &vT[((size_t)(bh * HD + d)) * TT + s0 + ss];
  *reinterpret_cast<short8*>(dst) = o0;
  *reinterpret_cast<short8*>(dst + 8) = o1;
}

// ---------------------------------------------------------------------------
// GEMM: C[M,N] = A[M,K] * Bt[N,K]^T + bias, BK=64, LDS [kh][128][32].
// Cols < QS get *0.125 (q pre-scale fold). 256 thr = 4 waves.
// ---------------------------------------------------------------------------
template <bool OUT_BF16>
__global__ __launch_bounds__(256) void gemm_bt_mfma(
    const short* __restrict__ A, const short* __restrict__ Bt,
    const float* __restrict__ bias, void* __restrict__ C, int M, int N, int K,
    int QS) {
  __shared__ __align__(16) short As[2 * 128 * 32];
  __shared__ __align__(16) short Bs[2 * 128 * 32];
  const int tid = threadIdx.x;
  const int w = tid >> 6, lane = tid & 63;
  const int quad = lane >> 4, l15 = lane & 15;
  const int m0 = blockIdx.y * 128, n0 = blockIdx.x * 128;
  const int wm = (w >> 1) * 64, wn = (w & 1) * 64;

  f32x4 acc[4][4] = {};
  const int row16 = lane >> 2;
  const int c4 = (lane & 3) * 8;

  for (int k0 = 0; k0 < K; k0 += 64) {
    __syncthreads();
#pragma unroll
    for (int p = 0; p < 2; ++p) {
      const int rbase = __builtin_amdgcn_readfirstlane((w * 2 + p) * 16);
#pragma unroll
      for (int kh = 0; kh < 2; ++kh) {
        const short* ga = &A[(size_t)(m0 + rbase + row16) * K + k0 + kh * 32 + c4];
        const short* gb = &Bt[(size_t)(n0 + rbase + row16) * K + k0 + kh * 32 + c4];
        __builtin_amdgcn_global_load_lds(
            (const __attribute__((address_space(1))) void*)ga,
            (__attribute__((address_space(3))) void*)&As[kh * 4096 + rbase * 32],
            16, 0, 0);
        __builtin_amdgcn_global_load_lds(
            (const __attribute__((address_space(1))) void*)gb,
            (__attribute__((address_space(3))) void*)&Bs[kh * 4096 + rbase * 32],
            16, 0, 0);
      }
    }
    __syncthreads();

    short8 af[2][4], bfr[2][4];
#pragma unroll
    for (int kh = 0; kh < 2; ++kh) {
#pragma unroll
      for (int i = 0; i < 4; ++i)
        af[kh][i] = *reinterpret_cast<const short8*>(
            &As[kh * 4096 + (wm + i * 16 + l15) * 32 + quad * 8]);
#pragma unroll
      for (int j = 0; j < 4; ++j)
        bfr[kh][j] = *reinterpret_cast<const short8*>(
            &Bs[kh * 4096 + (wn + j * 16 + l15) * 32 + quad * 8]);
    }
#pragma unroll
    for (int kh = 0; kh < 2; ++kh)
#pragma unroll
      for (int i = 0; i < 4; ++i)
#pragma unroll
        for (int j = 0; j < 4; ++j)
          acc[i][j] = MFMA16(af[kh][i], bfr[kh][j], acc[i][j], 0, 0, 0);
  }

#pragma unroll
  for (int i = 0; i < 4; ++i) {
#pragma unroll
    for (int r = 0; r < 4; ++r) {
      const int row = m0 + wm + i * 16 + quad * 4 + r;
#pragma unroll
      for (int j = 0; j < 4; ++j) {
        const int col = n0 + wn + j * 16 + l15;
        float v = acc[i][j][r] + bias[col];
        if (col < QS) v *= 0.125f;
        if (OUT_BF16)
          ((short*)C)[(size_t)row * N + col] = f2bf(v);
        else
          ((float*)C)[(size_t)row * N + col] = v;
      }
    }
  }
}

// ---------------------------------------------------------------------------
// MFMA flash attention v7: 256 thr = 4 waves, each wave 32 q (2 strips of 16)
// sharing K/V fragment reads (halves LDS reads/MFMA). 128-row q-tiles,
// within-block diagonal pairing (uniform 34 iters). PST=70 -> <=2-way banks.
// 1-D grid 256, n = bh + 32*px so a head's blocks share one XCD's L2.
// Fixed-m softmax (q pre-scaled 0.125 in GEMM); dbuf K/V, one barrier/iter.
// ---------------------------------------------------------------------------
#define PST 70
__global__ __launch_bounds__(256) void attn_mfma7(
    const short* __restrict__ qkv, const short* __restrict__ vT,
    const float* __restrict__ mask, short* __restrict__ y) {
  __shared__ __align__(16) short Ks[2][64 * PST];
  __shared__ __align__(16) short Vs[2][64 * PST];  // V^T tile [d][s]
  __shared__ __align__(16) short Ps[128 * PST];    // P [q_local][s]
  const int tid = threadIdx.x;
  const int w = tid >> 6, lane = tid & 63;
  const int quad = lane >> 4, l15 = lane & 15;
  const int n = blockIdx.x;
  const int bh = (n & 7) | (((n >> 3) & 3) << 3);  // n = bh + 32*px
  const int px = n >> 5;                           // 0..7
  const int b = bh >> 4, h = bh & 15;
  const int qh = 15 - px;                          // heavy q-tile (128 rows)
  const int nth = 2 * qh + 2;
  const int ntot = 34;                             // nth + 2*px+2, uniform
  const int RS = 3 * CC;

  int qt = qh;
  int qb = qt * 128 + w * 32;  // this wave's strip0 base (global q)

  // Q fragments per strip (pre-scaled by 0.125 in GEMM epilogue)
  short8 qf[2][2];
#pragma unroll
  for (int st = 0; st < 2; ++st) {
    const size_t qrow = (size_t)(b * TT + qb + st * 16 + l15) * RS + h * HD + quad * 8;
    qf[st][0] = *reinterpret_cast<const short8*>(&qkv[qrow]);
    qf[st][1] = *reinterpret_cast<const short8*>(&qkv[qrow + 32]);
  }

  float l_run[2] = {0.f, 0.f};
  f32x4 o_acc[2][4] = {};

  // staging: 256 threads, rows (sr, sr+32), one short8 each for K and V
  const int sr = tid >> 3, sc = (tid & 7) * 8;
  const short* kbase = qkv + (size_t)(b * TT + sr) * RS + CC + h * HD + sc;
  const short* vbase = vT + (size_t)(bh * HD + sr) * TT + sc;
  const float* mptr = mask + b * TT + quad * 4;
  const int kfo0 = quad * 8, kfo1 = 32 + quad * 8;

  // prefetch s-tile 0
  short8 kpre0 = *reinterpret_cast<const short8*>(kbase);
  short8 kpre1 = *reinterpret_cast<const short8*>(kbase + (size_t)32 * RS);
  short8 vpre0 = *reinterpret_cast<const short8*>(vbase);
  short8 vpre1 = *reinterpret_cast<const short8*>(vbase + 32 * TT);

  for (int it = 0; it < ntot; ++it) {
    const int kt = (it < nth) ? it : it - nth;
    const int s0 = kt * 64;

    if (it == nth) {
      // flush heavy-phase output (both strips), reset for light q-tile
#pragma unroll
      for (int st = 0; st < 2; ++st) {
#pragma unroll
        for (int r = 0; r < 4; ++r) {
          const float lr = __shfl(l_run[st], quad * 4 + r, 64);
          const float inv = 1.0f / lr;
          const size_t row = (size_t)(b * TT + qb + st * 16 + quad * 4 + r);
#pragma unroll
          for (int t = 0; t < 4; ++t)
            y[row * CC + h * HD + t * 16 + l15] = f2bf(o_acc[st][t][r] * inv);
        }
      }
      qt = px;
      qb = qt * 128 + w * 32;
#pragma unroll
      for (int st = 0; st < 2; ++st) {
        const size_t qrow = (size_t)(b * TT + qb + st * 16 + l15) * RS + h * HD + quad * 8;
        qf[st][0] = *reinterpret_cast<const short8*>(&qkv[qrow]);
        qf[st][1] = *reinterpret_cast<const short8*>(&qkv[qrow + 32]);
        l_run[st] = 0.f;
#pragma unroll
        for (int t = 0; t < 4; ++t) o_acc[st][t] = f32x4{0.f, 0.f, 0.f, 0.f};
      }
    }

    const int cur = it & 1;
    // stage tile `it`; ONE barrier per iteration (dbuf)
    *reinterpret_cast<short8*>(&Ks[cur][sr * PST + sc]) = kpre0;
    *reinterpret_cast<short8*>(&Ks[cur][(sr + 32) * PST + sc]) = kpre1;
    *reinterpret_cast<short8*>(&Vs[cur][sr * PST + sc]) = vpre0;
    *reinterpret_cast<short8*>(&Vs[cur][(sr + 32) * PST + sc]) = vpre1;
    __syncthreads();

    // prefetch tile it+1 (hides behind compute)
    if (it + 1 < ntot) {
      const int ktn = (it + 1 == nth) ? 0 : kt + 1;
      const short* kp = kbase + (size_t)ktn * 64 * RS;
      const short* vp = vbase + ktn * 64;
      kpre0 = *reinterpret_cast<const short8*>(kp);
      kpre1 = *reinterpret_cast<const short8*>(kp + (size_t)32 * RS);
      vpre0 = *reinterpret_cast<const short8*>(vp);
      vpre1 = *reinterpret_cast<const short8*>(vp + 32 * TT);
    }

    const bool act0 = (s0 <= qb + 15);
    const bool act1 = (s0 <= qb + 31);  // act0 implies act1
    if (!act1) continue;                // wave-uniform full skip

    // S^T = K Q'^T, K fragments shared across both strips
    f32x4 sa[2][4] = {};
#pragma unroll
    for (int j = 0; j < 4; ++j) {
      const short8 kf0 = *reinterpret_cast<const short8*>(
          &Ks[cur][(j * 16 + l15) * PST + kfo0]);
      const short8 kf1 = *reinterpret_cast<const short8*>(
          &Ks[cur][(j * 16 + l15) * PST + kfo1]);
      if (act0) {
        sa[0][j] = MFMA16(kf0, qf[0][0], sa[0][j], 0, 0, 0);
        sa[0][j] = MFMA16(kf1, qf[0][1], sa[0][j], 0, 0, 0);
      }
      sa[1][j] = MFMA16(kf0, qf[1][0], sa[1][j], 0, 0, 0);
      sa[1][j] = MFMA16(kf1, qf[1][1], sa[1][j], 0, 0, 0);
    }

    f32x4 mv[4];
#pragma unroll
    for (int j = 0; j < 4; ++j)
      mv[j] = *reinterpret_cast<const f32x4*>(&mptr[s0 + j * 16]);

    // fixed-m softmax per strip; truncating bf16 pack; l sums truncated p
#pragma unroll
    for (int st = 0; st < 2; ++st) {
      if (st == 0 && !act0) continue;
      const int qs = qb + st * 16;
      short* psrow = &Ps[(w * 32 + st * 16 + l15) * PST];
      float rs = 0.f;
      const bool boundary = (s0 + 63 > qs);
      const int qg = qs + l15;
#pragma unroll
      for (int j = 0; j < 4; ++j) {
        sh4 pw;
#pragma unroll
        for (int r = 0; r < 4; ++r) {
          float v = sa[st][j][r] + mv[j][r];
          if (boundary) {
            const int sg = s0 + j * 16 + quad * 4 + r;
            if (sg > qg) v = -10000.0f;
          }
          const float p = __expf(v);
          union { float f; unsigned u; } pu;
          pu.f = p;
          pw[r] = (short)(pu.u >> 16);
          pu.u &= 0xffff0000u;
          rs += pu.f;
        }
        *reinterpret_cast<sh4*>(&psrow[j * 16 + quad * 4]) = pw;
      }
      rs += __shfl_xor(rs, 16, 64);
      rs += __shfl_xor(rs, 32, 64);
      l_run[st] += rs;
    }

    // O += P V, V fragments shared across both strips
    short8 pf[2][2];
#pragma unroll
    for (int st = 0; st < 2; ++st) {
      if (st == 0 && !act0) continue;
      short* psrow = &Ps[(w * 32 + st * 16 + l15) * PST];
      pf[st][0] = *reinterpret_cast<const short8*>(&psrow[kfo0]);
      pf[st][1] = *reinterpret_cast<const short8*>(&psrow[kfo1]);
    }
#pragma unroll
    for (int t = 0; t < 4; ++t) {
      const short8 vf0 = *reinterpret_cast<const short8*>(
          &Vs[cur][(t * 16 + l15) * PST + kfo0]);
      const short8 vf1 = *reinterpret_cast<const short8*>(
          &Vs[cur][(t * 16 + l15) * PST + kfo1]);
      if (act0) {
        o_acc[0][t] = MFMA16(pf[0][0], vf0, o_acc[0][t], 0, 0, 0);
        o_acc[0][t] = MFMA16(pf[0][1], vf1, o_acc[0][t], 0, 0, 0);
      }
      o_acc[1][t] = MFMA16(pf[1][0], vf0, o_acc[1][t], 0, 0, 0);
      o_acc[1][t] = MFMA16(pf[1][1], vf1, o_acc[1][t], 0, 0, 0);
    }
  }

  // flush light-phase output (both strips)
#pragma unroll
  for (int st = 0; st < 2; ++st) {
#pragma unroll
    for (int r = 0; r < 4; ++r) {
      const float lr = __shfl(l_run[st], quad * 4 + r, 64);
      const float inv = 1.0f / lr;
      const size_t row = (size_t)(b * TT + qb + st * 16 + quad * 4 + r);
#pragma unroll
      for (int t = 0; t < 4; ++t)
        y[row * CC + h * HD + t * 16 + l15] = f2bf(o_acc[st][t][r] * inv);
    }
  }
}

extern "C" void kernel_launch(void* const* d_in, const int* in_sizes, int n_in,
                              void* d_out, int out_size, void* d_ws,
                              size_t ws_size, hipStream_t stream) {
  const float* x = (const float*)d_in[0];
  const float* attn_mask = (const float*)d_in[1];
  const float* W_attn = (const float*)d_in[2];
  const float* b_attn = (const float*)d_in[3];
  const float* W_proj = (const float*)d_in[4];
  const float* b_proj = (const float*)d_in[5];
  float* out = (float*)d_out;

  const int M = BATCH * TT;  // 4096

  short* xb = (short*)d_ws;                       // [4096,1024]
  short* wat = xb + (size_t)M * CC;               // [3072,1024]
  short* wpt = wat + (size_t)(3 * CC) * CC;       // [1024,1024]
  short* qkvb = wpt + (size_t)CC * CC;            // [4096,3072]
  short* yb = qkvb + (size_t)M * 3 * CC;          // [4096,1024]
  short* vTb = yb + (size_t)M * CC;               // [2*16*64, 2048]

  prep_fused<<<3072, 256, 0, stream>>>(x, xb, W_attn, wat, W_proj, wpt);

  // qkv = x @ W_attn + b_attn; q-third scaled by 0.125 (folded attn scale)
  gemm_bt_mfma<true><<<dim3((3 * CC) / 128, M / 128), 256, 0, stream>>>(
      xb, wat, b_attn, qkvb, M, 3 * CC, CC, CC);

  transpose_v<<<dim3(TT / 64, BATCH * NH), 256, 0, stream>>>(qkvb, vTb);

  attn_mfma7<<<256, 256, 0, stream>>>(qkvb, vTb, attn_mask, yb);

  gemm_bt_mfma<false><<<dim3(CC / 128, M / 128), 256, 0, stream>>>(
      yb, wpt, b_proj, out, M, CC, CC, 0);
}